// Round 1
// baseline (535.528 us; speedup 1.0000x reference)
//
#include <hip/hip_runtime.h>
#include <math.h>

#define EPSF 1e-8f
#define Bn 2
#define Tn 512
#define Dn 64
#define Ln 4
#define ROWS (Bn*Tn)
#define NELEM (Bn*Tn*Dn)

__device__ __forceinline__ float sigmoidf_(float x){ return 1.0f/(1.0f+expf(-x)); }
__device__ __forceinline__ float softplusf_(float x){ return fmaxf(x,0.0f) + log1pf(expf(-fabsf(x))); }

__device__ __forceinline__ float waveReduceSum(float v){
  #pragma unroll
  for (int off=1; off<64; off<<=1) v += __shfl_xor(v, off, 64);
  return v;
}

// ---- pass-1 feedback gate: x = x*g + prev*(1-g), g = sigmoid([x,prev] @ W_fb[l].T + b_fb[l])
__global__ void k_fbgate(float* __restrict__ x, const float* __restrict__ prev,
                         const float* __restrict__ W_fb, const float* __restrict__ b_fb, int l){
  int row = blockIdx.x;           // 0..ROWS-1
  int d = threadIdx.x;            // 0..63
  __shared__ __align__(16) float comb[128];
  float xv = x[row*Dn + d];
  float pv = prev[row*Dn + d];
  comb[d] = xv; comb[64+d] = pv;
  __syncthreads();
  const float4* W  = (const float4*)(W_fb + (size_t)l*Dn*2*Dn + (size_t)d*2*Dn);
  const float4* c4 = (const float4*)comb;
  float acc = 0.f;
  #pragma unroll
  for (int k=0;k<32;k++){ float4 w=W[k], c=c4[k]; acc += w.x*c.x + w.y*c.y + w.z*c.z + w.w*c.w; }
  float g = sigmoidf_(acc + b_fb[l*Dn + d]);
  x[row*Dn + d] = xv*g + pv*(1.0f-g);
}

// ---- per-pass temperatures: temps[l] = sigmoid(W_temp[l]·cb + b_temp[l]) + 0.5
__global__ void k_temps(const float* __restrict__ W_temp, const float* __restrict__ b_temp,
                        const float* __restrict__ cb, float* __restrict__ temps){
  int d = threadIdx.x;            // 64 threads
  float cbv = cb[d];
  for (int l=0;l<Ln;l++){
    float v = W_temp[l*Dn + d]*cbv;
    v = waveReduceSum(v);
    if (d==0) temps[l] = sigmoidf_(v + b_temp[l]) + 0.5f;
  }
}

// ---- simplex projection + renormalize (matches reference exactly)
__global__ void k_pnorm(const float* __restrict__ x, float* __restrict__ pn){
  int row = blockIdx.x; int d = threadIdx.x;   // 64 threads
  float s = softplusf_(x[row*Dn+d]);
  float sum = waveReduceSum(s);
  float p = s/(sum+EPSF);
  p = fmaxf(p, EPSF);
  float sum2 = waveReduceSum(p);
  pn[row*Dn+d] = p/(sum2+EPSF);
}

// ---- QFI attention + residual for one (b,i) row per block (256 threads)
__global__ void __launch_bounds__(256) k_attn(
                       const float* __restrict__ xin, const float* __restrict__ pn,
                       const float* __restrict__ temps, const float* __restrict__ res_scale,
                       float* __restrict__ xout, float* __restrict__ state, int l){
  int row = blockIdx.x;       // b*T + i
  int b = row >> 9;           // T = 512
  int tid = threadIdx.x;
  __shared__ __align__(16) float p_i[64];
  __shared__ float lg[512];
  __shared__ float red[256];
  if (tid < 64) p_i[tid] = pn[row*Dn + tid];
  __syncthreads();
  float invT = 1.0f / fmaxf(temps[l], 1e-6f);
  const float4* p4base = (const float4*)(pn + (size_t)b*Tn*Dn);
  const float4* pi4 = (const float4*)p_i;
  float lmax = -1e30f;
  for (int j = tid; j < Tn; j += 256){
    const float4* pj = p4base + j*16;
    float inner = 0.f;
    #pragma unroll
    for (int k=0;k<16;k++){
      float4 a = pi4[k]; float4 c = pj[k];
      inner += sqrtf(a.x*c.x + EPSF) + sqrtf(a.y*c.y + EPSF)
             + sqrtf(a.z*c.z + EPSF) + sqrtf(a.w*c.w + EPSF);
    }
    inner = fminf(fmaxf(inner, -1.0f+1e-6f), 1.0f-1e-6f);
    float logit = -2.0f*acosf(inner)*invT;
    lg[j] = logit;
    lmax = fmaxf(lmax, logit);
  }
  red[tid] = lmax; __syncthreads();
  #pragma unroll
  for (int s=128; s>0; s>>=1){ if (tid<s) red[tid]=fmaxf(red[tid],red[tid+s]); __syncthreads(); }
  float maxv = red[0]; __syncthreads();
  float lsum = 0.f;
  for (int j = tid; j < Tn; j += 256){
    float e = expf(lg[j]-maxv); lg[j]=e; lsum += e;
  }
  red[tid]=lsum; __syncthreads();
  #pragma unroll
  for (int s=128; s>0; s>>=1){ if (tid<s) red[tid]+=red[tid+s]; __syncthreads(); }
  float invSum = 1.0f/red[0];
  __syncthreads();
  // x_attn: 4 waves each take a quarter of j, 64 lanes cover d
  int d = tid & 63, q = tid >> 6;
  const float* xb = xin + (size_t)b*Tn*Dn;
  float acc = 0.f;
  for (int j = q*128; j < q*128+128; ++j) acc += lg[j]*xb[j*Dn + d];
  red[tid] = acc; __syncthreads();
  if (tid < 64){
    float attn = (red[tid]+red[64+tid]+red[128+tid]+red[192+tid])*invSum;
    float xi = xin[row*Dn + tid];
    float rs = res_scale[l];
    float o = xi + rs*(attn - xi);
    xout[row*Dn + tid] = o;
    if (state) state[row*Dn + tid] = o;
  }
}

// ---- pool + compress MLP + basin update (only needed after pass 0)
__global__ void k_basin(const float* __restrict__ x,
                        const float* __restrict__ Wc1, const float* __restrict__ bc1,
                        const float* __restrict__ Wc2, const float* __restrict__ bc2,
                        const float* __restrict__ Wu,  const float* __restrict__ bu,
                        const float* __restrict__ cb_in, float* __restrict__ cb_out){
  int tid = threadIdx.x; // 256
  __shared__ float pooled[128];   // B*D
  __shared__ float h1[64];        // B*H (H=32)
  __shared__ float hb[128];       // B*D
  __shared__ float comb[128];
  if (tid < 128){
    int b = tid >> 6, d = tid & 63;
    float acc=0.f;
    const float* xb = x + (size_t)b*Tn*Dn + d;
    for (int t=0;t<Tn;t++) acc += xb[t*Dn];
    pooled[tid] = acc * (1.0f/Tn);
  }
  __syncthreads();
  if (tid < 64){
    int b = tid >> 5, h = tid & 31;
    float acc=0.f;
    #pragma unroll 8
    for (int d2=0; d2<Dn; d2++) acc += pooled[b*64+d2]*Wc1[h*Dn+d2];
    h1[tid] = tanhf(acc + bc1[h]);
  }
  __syncthreads();
  if (tid < 128){
    int b = tid >> 6, d = tid & 63;
    float acc=0.f;
    #pragma unroll 8
    for (int h2=0; h2<32; h2++) acc += h1[b*32+h2]*Wc2[d*32+h2];
    hb[tid] = tanhf(acc + bc2[d]);
  }
  __syncthreads();
  if (tid < 64){
    float agg = 0.5f*(hb[tid] + hb[64+tid]);
    comb[tid] = cb_in[tid];
    comb[64+tid] = agg;
  }
  __syncthreads();
  if (tid < 64){
    float acc=0.f;
    #pragma unroll 8
    for (int k=0;k<128;k++) acc += Wu[tid*128+k]*comb[k];
    float g = sigmoidf_(acc + bu[tid]);
    cb_out[tid] = comb[tid]*(1.0f-g) + comb[64+tid]*g;
  }
}

// ---- final global residual
__global__ void k_final(const float* __restrict__ x, const float* __restrict__ basin_seq,
                        const float* __restrict__ rsg, float* __restrict__ out){
  int i = blockIdx.x*blockDim.x + threadIdx.x;
  float c = 0.01f * rsg[0];
  float xv = x[i], bs = basin_seq[i];
  out[i] = xv + c*(xv - bs);
}

extern "C" void kernel_launch(void* const* d_in, const int* in_sizes, int n_in,
                              void* d_out, int out_size, void* d_ws, size_t ws_size,
                              hipStream_t stream) {
  const float* basin_seq    = (const float*)d_in[0];
  const float* basin_coords = (const float*)d_in[1];
  const float* W_temp       = (const float*)d_in[2];
  const float* b_temp       = (const float*)d_in[3];
  const float* res_scale    = (const float*)d_in[4];
  const float* W_fb         = (const float*)d_in[5];
  const float* b_fb         = (const float*)d_in[6];
  const float* Wc1          = (const float*)d_in[7];
  const float* bc1          = (const float*)d_in[8];
  const float* Wc2          = (const float*)d_in[9];
  const float* bc2          = (const float*)d_in[10];
  const float* Wu           = (const float*)d_in[11];
  const float* bu           = (const float*)d_in[12];
  const float* rsg          = (const float*)d_in[13];
  float* out = (float*)d_out;
  float* ws  = (float*)d_ws;

  const int N = NELEM; // 65536
  float* xA    = ws;
  float* xB    = ws + (size_t)N;
  float* pn    = ws + (size_t)2*N;
  float* st    = ws + (size_t)3*N;      // 4 layer states (pass 0): 4*N
  float* temps = ws + (size_t)7*N;      // 4 floats (padded)
  float* cb    = ws + (size_t)7*N + 64; // 64 floats

  const float* xcur = basin_seq;
  float* bufs[2] = {xA, xB};
  int parity = 0;

  for (int p=0; p<2; ++p){
    k_temps<<<1,64,0,stream>>>(W_temp, b_temp, p==0 ? basin_coords : cb, temps);
    for (int l=0; l<Ln; ++l){
      if (p==1){
        // xcur is a ws buffer by pass 1 (pass 0 did 4 swaps) — in-place is safe per-row
        k_fbgate<<<ROWS,64,0,stream>>>((float*)xcur, st + (size_t)l*N, W_fb, b_fb, l);
      }
      k_pnorm<<<ROWS,64,0,stream>>>(xcur, pn);
      float* xnext = bufs[parity];
      k_attn<<<ROWS,256,0,stream>>>(xcur, pn, temps, res_scale, xnext,
                                    p==0 ? (st + (size_t)l*N) : nullptr, l);
      xcur = xnext; parity ^= 1;
    }
    if (p==0){
      k_basin<<<1,256,0,stream>>>(xcur, Wc1, bc1, Wc2, bc2, Wu, bu, basin_coords, cb);
    }
  }
  k_final<<<NELEM/256,256,0,stream>>>(xcur, basin_seq, rsg, out);
}

// Round 2
// 337.193 us; speedup vs baseline: 1.5882x; 1.5882x over previous
//
#include <hip/hip_runtime.h>
#include <math.h>

#define EPSF 1e-8f
#define Bn 2
#define Tn 512
#define Dn 64
#define Ln 4
#define ROWS (Bn*Tn)
#define NELEM (Bn*Tn*Dn)

__device__ __forceinline__ float sigmoidf_(float x){ return 1.0f/(1.0f+expf(-x)); }
__device__ __forceinline__ float softplusf_(float x){ return fmaxf(x,0.0f) + log1pf(expf(-fabsf(x))); }

__device__ __forceinline__ float waveReduceSum(float v){
  #pragma unroll
  for (int off=1; off<64; off<<=1) v += __shfl_xor(v, off, 64);
  return v;
}
__device__ __forceinline__ float waveReduceMax(float v){
  #pragma unroll
  for (int off=1; off<64; off<<=1) v = fmaxf(v, __shfl_xor(v, off, 64));
  return v;
}

// ---- initial temperatures (pass 0): temps[l] = sigmoid(W_temp[l]·cb + b_temp[l]) + 0.5
__global__ void k_temps(const float* __restrict__ W_temp, const float* __restrict__ b_temp,
                        const float* __restrict__ cb, float* __restrict__ temps){
  int d = threadIdx.x;            // 64 threads
  float cbv = cb[d];
  #pragma unroll
  for (int l=0;l<Ln;l++){
    float v = W_temp[l*Dn + d]*cbv;
    v = waveReduceSum(v);
    if (d==0) temps[l] = sigmoidf_(v + b_temp[l]) + 0.5f;
  }
}

// ---- simplex projection; writes s = sqrt(p_renorm)
__global__ void k_pnorm(const float* __restrict__ x, float* __restrict__ sbuf){
  int row = blockIdx.x; int d = threadIdx.x;   // 64 threads
  float s = softplusf_(x[row*Dn+d]);
  float sum = waveReduceSum(s);
  float p = s/(sum+EPSF);
  p = fmaxf(p, EPSF);
  float sum2 = waveReduceSum(p);
  sbuf[row*Dn+d] = sqrtf(p/(sum2+EPSF));
}

// ---- pass-1 prep: feedback gate (in place) + simplex projection
__global__ void k_prep(float* __restrict__ x, const float* __restrict__ prev,
                       const float* __restrict__ W_fb, const float* __restrict__ b_fb,
                       float* __restrict__ sbuf, int l){
  int row = blockIdx.x; int d = threadIdx.x;   // 64 threads
  __shared__ __align__(16) float comb[128];
  float xv = x[row*Dn + d];
  float pv = prev[row*Dn + d];
  comb[d] = xv; comb[64+d] = pv;
  __syncthreads();
  const float4* W  = (const float4*)(W_fb + (size_t)l*Dn*2*Dn + (size_t)d*2*Dn);
  const float4* c4 = (const float4*)comb;
  float a0=0.f,a1=0.f;
  #pragma unroll
  for (int k=0;k<32;k+=2){
    float4 w=W[k],   c=c4[k];   a0 += w.x*c.x + w.y*c.y + w.z*c.z + w.w*c.w;
    float4 w2=W[k+1],c2=c4[k+1];a1 += w2.x*c2.x + w2.y*c2.y + w2.z*c2.z + w2.w*c2.w;
  }
  float g = sigmoidf_(a0+a1 + b_fb[l*Dn + d]);
  float xn = xv*g + pv*(1.0f-g);
  x[row*Dn + d] = xn;
  float s = softplusf_(xn);
  float sum = waveReduceSum(s);
  float p = s/(sum+EPSF);
  p = fmaxf(p, EPSF);
  float sum2 = waveReduceSum(p);
  sbuf[row*Dn+d] = sqrtf(p/(sum2+EPSF));
}

// ---- QFI attention + residual; one (b,i) row per 256-thread block
__global__ void __launch_bounds__(256) k_attn(
                       const float* __restrict__ xin, const float* __restrict__ sbuf,
                       const float* __restrict__ temps, const float* __restrict__ res_scale,
                       float* __restrict__ xout, float* __restrict__ state, int l,
                       const float* __restrict__ basin_seq, const float* __restrict__ rsg){
  int row = blockIdx.x;       // b*T + i
  int b = row >> 9;           // T = 512
  int tid = threadIdx.x;
  int wid = tid >> 6;
  __shared__ __align__(16) float s_i[64];
  __shared__ float lg[512];
  __shared__ float red[256];
  __shared__ float redw[8];
  if (tid < 64) s_i[tid] = sbuf[row*Dn + tid];
  __syncthreads();
  float invT = 1.0f / fmaxf(temps[l], 1e-6f);
  const float4* s4base = (const float4*)(sbuf + (size_t)b*Tn*Dn);
  const float4* si4 = (const float4*)s_i;
  // --- loop 1: inner products for j = tid and tid+256 (4 independent FMA chains)
  int j0 = tid, j1 = tid + 256;
  const float4* pj0 = s4base + j0*16;
  const float4* pj1 = s4base + j1*16;
  float a00=0.f,a01=0.f,a10=0.f,a11=0.f;
  #pragma unroll
  for (int k=0;k<16;k+=2){
    float4 s0=si4[k], s1=si4[k+1];
    float4 c00=pj0[k], c01=pj0[k+1], c10=pj1[k], c11=pj1[k+1];
    a00 += s0.x*c00.x + s0.y*c00.y + s0.z*c00.z + s0.w*c00.w;
    a01 += s1.x*c01.x + s1.y*c01.y + s1.z*c01.z + s1.w*c01.w;
    a10 += s0.x*c10.x + s0.y*c10.y + s0.z*c10.z + s0.w*c10.w;
    a11 += s1.x*c11.x + s1.y*c11.y + s1.z*c11.z + s1.w*c11.w;
  }
  float in0 = fminf(fmaxf(a00+a01, -1.0f+1e-6f), 1.0f-1e-6f);
  float in1 = fminf(fmaxf(a10+a11, -1.0f+1e-6f), 1.0f-1e-6f);
  float l0 = -2.0f*acosf(in0)*invT;
  float l1 = -2.0f*acosf(in1)*invT;
  // --- max reduce (wave shuffle + 4-way LDS)
  float lmax = waveReduceMax(fmaxf(l0, l1));
  if ((tid & 63) == 0) redw[wid] = lmax;
  __syncthreads();
  float maxv = fmaxf(fmaxf(redw[0],redw[1]), fmaxf(redw[2],redw[3]));
  float e0 = expf(l0 - maxv), e1 = expf(l1 - maxv);
  lg[j0] = e0; lg[j1] = e1;
  float lsum = waveReduceSum(e0 + e1);
  if ((tid & 63) == 0) redw[4 + wid] = lsum;
  __syncthreads();
  float invSum = 1.0f/(redw[4]+redw[5]+redw[6]+redw[7]);
  // --- PV: 4 waves each take a quarter of j, 64 lanes cover d
  int d = tid & 63, q = wid;
  const float* xb = xin + (size_t)b*Tn*Dn + d;
  float p0=0.f,p1=0.f,p2=0.f,p3=0.f;
  int jb = q*128;
  #pragma unroll 8
  for (int j = jb; j < jb+128; j += 4){
    p0 += lg[j]  *xb[(size_t)j*Dn];
    p1 += lg[j+1]*xb[(size_t)(j+1)*Dn];
    p2 += lg[j+2]*xb[(size_t)(j+2)*Dn];
    p3 += lg[j+3]*xb[(size_t)(j+3)*Dn];
  }
  red[tid] = (p0+p1)+(p2+p3);
  __syncthreads();
  if (tid < 64){
    float attn = (red[tid]+red[64+tid]+red[128+tid]+red[192+tid])*invSum;
    float xi = xin[row*Dn + tid];
    float rs = res_scale[l];
    float o = xi + rs*(attn - xi);
    if (basin_seq){  // fused final residual (last layer-pass)
      float c = 0.01f * rsg[0];
      xout[row*Dn + tid] = o + c*(o - basin_seq[row*Dn + tid]);
    } else {
      xout[row*Dn + tid] = o;
    }
    if (state) state[row*Dn + tid] = o;
  }
}

// ---- pool + compress MLP + basin update + pass-1 temperatures
__global__ void k_basin(const float* __restrict__ x,
                        const float* __restrict__ Wc1, const float* __restrict__ bc1,
                        const float* __restrict__ Wc2, const float* __restrict__ bc2,
                        const float* __restrict__ Wu,  const float* __restrict__ bu,
                        const float* __restrict__ cb_in, float* __restrict__ cb_out,
                        const float* __restrict__ W_temp, const float* __restrict__ b_temp,
                        float* __restrict__ temps){
  int tid = threadIdx.x; // 256
  __shared__ float pooled[128];   // B*D
  __shared__ float h1[64];        // B*H (H=32)
  __shared__ float hb[128];       // B*D
  __shared__ float comb[128];
  if (tid < 128){
    int b = tid >> 6, d = tid & 63;
    float acc=0.f;
    const float* xb = x + (size_t)b*Tn*Dn + d;
    for (int t=0;t<Tn;t++) acc += xb[t*Dn];
    pooled[tid] = acc * (1.0f/Tn);
  }
  __syncthreads();
  if (tid < 64){
    int b = tid >> 5, h = tid & 31;
    float acc=0.f;
    #pragma unroll 8
    for (int d2=0; d2<Dn; d2++) acc += pooled[b*64+d2]*Wc1[h*Dn+d2];
    h1[tid] = tanhf(acc + bc1[h]);
  }
  __syncthreads();
  if (tid < 128){
    int b = tid >> 6, d = tid & 63;
    float acc=0.f;
    #pragma unroll 8
    for (int h2=0; h2<32; h2++) acc += h1[b*32+h2]*Wc2[d*32+h2];
    hb[tid] = tanhf(acc + bc2[d]);
  }
  __syncthreads();
  if (tid < 64){
    float agg = 0.5f*(hb[tid] + hb[64+tid]);
    comb[tid] = cb_in[tid];
    comb[64+tid] = agg;
  }
  __syncthreads();
  if (tid < 64){
    float acc=0.f;
    #pragma unroll 8
    for (int k=0;k<128;k++) acc += Wu[tid*128+k]*comb[k];
    float g = sigmoidf_(acc + bu[tid]);
    float nb = comb[tid]*(1.0f-g) + comb[64+tid]*g;
    cb_out[tid] = nb;
    // pass-1 temperatures (wave 0 only)
    #pragma unroll
    for (int l=0;l<Ln;l++){
      float v = waveReduceSum(W_temp[l*Dn + tid]*nb);
      if (tid==0) temps[l] = sigmoidf_(v + b_temp[l]) + 0.5f;
    }
  }
}

extern "C" void kernel_launch(void* const* d_in, const int* in_sizes, int n_in,
                              void* d_out, int out_size, void* d_ws, size_t ws_size,
                              hipStream_t stream) {
  const float* basin_seq    = (const float*)d_in[0];
  const float* basin_coords = (const float*)d_in[1];
  const float* W_temp       = (const float*)d_in[2];
  const float* b_temp       = (const float*)d_in[3];
  const float* res_scale    = (const float*)d_in[4];
  const float* W_fb         = (const float*)d_in[5];
  const float* b_fb         = (const float*)d_in[6];
  const float* Wc1          = (const float*)d_in[7];
  const float* bc1          = (const float*)d_in[8];
  const float* Wc2          = (const float*)d_in[9];
  const float* bc2          = (const float*)d_in[10];
  const float* Wu           = (const float*)d_in[11];
  const float* bu           = (const float*)d_in[12];
  const float* rsg          = (const float*)d_in[13];
  float* out = (float*)d_out;
  float* ws  = (float*)d_ws;

  const int N = NELEM; // 65536
  float* xA    = ws;
  float* xB    = ws + (size_t)N;
  float* sn    = ws + (size_t)2*N;
  float* st    = ws + (size_t)3*N;      // 4 layer states (pass 0)
  float* temps = ws + (size_t)7*N;      // 4 floats
  float* cb    = ws + (size_t)7*N + 64; // 64 floats

  const float* xcur = basin_seq;
  float* bufs[2] = {xA, xB};
  int parity = 0;

  // ---- pass 0
  k_temps<<<1,64,0,stream>>>(W_temp, b_temp, basin_coords, temps);
  for (int l=0; l<Ln; ++l){
    k_pnorm<<<ROWS,64,0,stream>>>(xcur, sn);
    float* xnext = bufs[parity];
    k_attn<<<ROWS,256,0,stream>>>(xcur, sn, temps, res_scale, xnext,
                                  st + (size_t)l*N, l, nullptr, nullptr);
    xcur = xnext; parity ^= 1;
  }
  k_basin<<<1,256,0,stream>>>(xcur, Wc1, bc1, Wc2, bc2, Wu, bu,
                              basin_coords, cb, W_temp, b_temp, temps);
  // ---- pass 1
  for (int l=0; l<Ln; ++l){
    k_prep<<<ROWS,64,0,stream>>>((float*)xcur, st + (size_t)l*N, W_fb, b_fb, sn, l);
    bool last = (l == Ln-1);
    float* xnext = last ? out : bufs[parity];
    k_attn<<<ROWS,256,0,stream>>>(xcur, sn, temps, res_scale, xnext,
                                  nullptr, l,
                                  last ? basin_seq : nullptr,
                                  last ? rsg : nullptr);
    xcur = xnext; parity ^= 1;
  }
}